// Round 1
// baseline (1231.483 us; speedup 1.0000x reference)
//
#include <hip/hip_runtime.h>

#define V 4096
#define H 256
#define O 512
#define B 64
#define T 512

typedef __attribute__((ext_vector_type(8))) short bf16x8;
typedef __attribute__((ext_vector_type(4))) float f32x4;

__device__ __forceinline__ unsigned short f2bf(float f) {
    unsigned int u = __float_as_uint(f);
    u += 0x7fffu + ((u >> 16) & 1u);   // round-to-nearest-even
    return (unsigned short)(u >> 16);
}
__device__ __forceinline__ float bf2f(unsigned short s) {
    return __uint_as_float(((unsigned int)s) << 16);
}

// ---------------------------------------------------------------------------
// K1a: transpose W_ih [H=256][V=4096] -> WihT [V][H] so the per-step gather
// row read in k_rnn is coalesced (1 KB contiguous per row).
// ---------------------------------------------------------------------------
__global__ __launch_bounds__(256) void k_transpose(const float* __restrict__ Wih,
                                                   float* __restrict__ WihT) {
    __shared__ float tile[64][65];
    const int bi = blockIdx.x & 3;        // i-tile (4 of 64)
    const int bv = blockIdx.x >> 2;       // v-tile (64 of 64)
    const int tx = threadIdx.x & 63, ty = threadIdx.x >> 6;
#pragma unroll
    for (int s = 0; s < 16; ++s) {
        int r = ty + 4 * s;
        tile[r][tx] = Wih[(size_t)(bi * 64 + r) * V + bv * 64 + tx];
    }
    __syncthreads();
#pragma unroll
    for (int s = 0; s < 16; ++s) {
        int r = ty + 4 * s;
        WihT[(size_t)(bv * 64 + r) * H + bi * 64 + tx] = tile[tx][r];
    }
}

// ---------------------------------------------------------------------------
// K1b: split W_fc into bf16 hi + bf16 lo (3-MFMA split gives ~2^-17 rel err).
// ---------------------------------------------------------------------------
__global__ __launch_bounds__(256) void k_prep(const float* __restrict__ Wfc,
                                              unsigned short* __restrict__ hi,
                                              unsigned short* __restrict__ lo) {
    int i = blockIdx.x * 256 + threadIdx.x;   // 512 blocks * 256 = 131072 = O*H
    float w = Wfc[i];
    unsigned short h = f2bf(w);
    hi[i] = h;
    lo[i] = f2bf(w - bf2f(h));
}

// ---------------------------------------------------------------------------
// K2: persistent RNN. 64 blocks (one per batch), 256 threads (one per h-elem).
// W_hh row lives in 256 VGPRs per thread; h broadcast via LDS double buffer.
// Stores hs as bf16 hi/lo for the MFMA FC kernel.
// ---------------------------------------------------------------------------
__global__ __launch_bounds__(256, 1) void k_rnn(
    const int* __restrict__ x, const float* __restrict__ WihT,
    const float* __restrict__ Whh, const float* __restrict__ b_ih,
    const float* __restrict__ b_hh,
    unsigned short* __restrict__ hs_hi, unsigned short* __restrict__ hs_lo) {
    __shared__ float hsm[2][H];
    __shared__ int xs[T];
    const int b = blockIdx.x;
    const int i = threadIdx.x;

    // W_hh row i -> 64 float4 = 256 VGPRs (one-time, L2-amortized across blocks)
    float4 wv[64];
    {
        const float4* wr = (const float4*)(Whh + (size_t)i * H);
#pragma unroll
        for (int j = 0; j < 64; ++j) wv[j] = wr[j];
    }
    xs[i]       = x[b * T + i];
    xs[i + 256] = x[b * T + i + 256];
    hsm[0][i] = 0.0f;
    const float bias = b_ih[i] + b_hh[i];
    __syncthreads();

    unsigned short* ph = hs_hi + (size_t)b * T * H + i;
    unsigned short* pl = hs_lo + (size_t)b * T * H + i;

    for (int t = 0; t < T; ++t) {
        // xp gather: issued at loop top, consumed after the 512-cyc dot -> hidden
        float xp = WihT[(size_t)xs[t] * H + i];
        const float4* hv = (const float4*)hsm[t & 1];
        float a0 = 0.f, a1 = 0.f, a2 = 0.f, a3 = 0.f;
#pragma unroll
        for (int j = 0; j < 64; ++j) {
            float4 h4 = hv[j];   // same-addr LDS read: broadcast, conflict-free
            a0 = fmaf(h4.x, wv[j].x, a0);
            a1 = fmaf(h4.y, wv[j].y, a1);
            a2 = fmaf(h4.z, wv[j].z, a2);
            a3 = fmaf(h4.w, wv[j].w, a3);
        }
        float pre = xp + bias + ((a0 + a1) + (a2 + a3));
        // tanh(x) = 1 - 2/(e^{2x}+1); saturates correctly for |pre| large
        float e = __expf(2.0f * pre);
        float h = 1.0f - 2.0f / (e + 1.0f);
        hsm[(t + 1) & 1][i] = h;      // write other buffer: no race with reads
        unsigned short hh = f2bf(h);
        ph[(size_t)t * H] = hh;
        pl[(size_t)t * H] = f2bf(h - bf2f(hh));
        __syncthreads();              // single barrier per step (double buffer)
    }
}

// ---------------------------------------------------------------------------
// K3: FC GEMM [32768,256] x [256,512] via 3-split bf16 MFMA.
// 128x128 tile, BK=64, 4 waves (2x2, 64x64 each), XOR-swizzled LDS.
// ---------------------------------------------------------------------------
__global__ __launch_bounds__(256, 2) void k_fc(
    const unsigned short* __restrict__ hs_hi, const unsigned short* __restrict__ hs_lo,
    const unsigned short* __restrict__ wfc_hi, const unsigned short* __restrict__ wfc_lo,
    const float* __restrict__ b_fc, float* __restrict__ out) {
    __shared__ short sAh[128 * 64], sAl[128 * 64], sBh[128 * 64], sBl[128 * 64];
    const int tid = threadIdx.x;
    const int bm = blockIdx.x >> 2, bn = blockIdx.x & 3;
    const int m0 = bm * 128, n0 = bn * 128;
    const int w = tid >> 6, lane = tid & 63;
    const int wm = w >> 1, wn = w & 1;
    const int l16 = lane & 15, g = lane >> 4;

    f32x4 acc[4][4];
#pragma unroll
    for (int a = 0; a < 4; ++a)
#pragma unroll
        for (int c = 0; c < 4; ++c)
#pragma unroll
            for (int q = 0; q < 4; ++q) acc[a][c][q] = 0.0f;

    for (int kt = 0; kt < 4; ++kt) {
        const int k0 = kt * 64;
        // stage 4 tiles of [128 rows][64 k] bf16; 16B chunks, XOR swizzle on
        // the 16B slot index by (row&7): conflict-free b128 reads (BW floor).
#pragma unroll
        for (int s = 0; s < 4; ++s) {
            int c = tid + 256 * s;
            int r = c >> 3, slot = c & 7;
            int dst = r * 64 + ((slot ^ (r & 7)) << 3);
            size_t ga = (size_t)(m0 + r) * 256 + k0 + slot * 8;
            *(bf16x8*)&sAh[dst] = *(const bf16x8*)&hs_hi[ga];
            *(bf16x8*)&sAl[dst] = *(const bf16x8*)&hs_lo[ga];
            size_t gb = (size_t)(n0 + r) * 256 + k0 + slot * 8;
            *(bf16x8*)&sBh[dst] = *(const bf16x8*)&wfc_hi[gb];
            *(bf16x8*)&sBl[dst] = *(const bf16x8*)&wfc_lo[gb];
        }
        __syncthreads();
#pragma unroll
        for (int kc = 0; kc < 2; ++kc) {
            bf16x8 ah[4], al[4], bh[4], bl[4];
            const int slot = kc * 4 + g;
#pragma unroll
            for (int mi = 0; mi < 4; ++mi) {
                int r = wm * 64 + mi * 16 + l16;
                int off = r * 64 + ((slot ^ (r & 7)) << 3);
                ah[mi] = *(const bf16x8*)&sAh[off];
                al[mi] = *(const bf16x8*)&sAl[off];
            }
#pragma unroll
            for (int ni = 0; ni < 4; ++ni) {
                int r = wn * 64 + ni * 16 + l16;
                int off = r * 64 + ((slot ^ (r & 7)) << 3);
                bh[ni] = *(const bf16x8*)&sBh[off];
                bl[ni] = *(const bf16x8*)&sBl[off];
            }
#pragma unroll
            for (int mi = 0; mi < 4; ++mi)
#pragma unroll
                for (int ni = 0; ni < 4; ++ni) {
                    acc[mi][ni] = __builtin_amdgcn_mfma_f32_16x16x32_bf16(
                        ah[mi], bh[ni], acc[mi][ni], 0, 0, 0);
                    acc[mi][ni] = __builtin_amdgcn_mfma_f32_16x16x32_bf16(
                        ah[mi], bl[ni], acc[mi][ni], 0, 0, 0);
                    acc[mi][ni] = __builtin_amdgcn_mfma_f32_16x16x32_bf16(
                        al[mi], bh[ni], acc[mi][ni], 0, 0, 0);
                }
        }
        __syncthreads();
    }
    // epilogue: C/D layout col = lane&15, row = (lane>>4)*4 + reg  [m89-verified]
#pragma unroll
    for (int ni = 0; ni < 4; ++ni) {
        int n = n0 + wn * 64 + ni * 16 + l16;
        float bfc = b_fc[n];
#pragma unroll
        for (int mi = 0; mi < 4; ++mi) {
#pragma unroll
            for (int q = 0; q < 4; ++q) {
                int m = m0 + wm * 64 + mi * 16 + g * 4 + q;
                out[(size_t)m * O + n] = acc[mi][ni][q] + bfc;
            }
        }
    }
}

extern "C" void kernel_launch(void* const* d_in, const int* in_sizes, int n_in,
                              void* d_out, int out_size, void* d_ws, size_t ws_size,
                              hipStream_t stream) {
    (void)in_sizes; (void)n_in; (void)out_size; (void)ws_size;
    const int*   x    = (const int*)d_in[0];
    const float* Wih  = (const float*)d_in[1];
    const float* Whh  = (const float*)d_in[2];
    const float* bih  = (const float*)d_in[3];
    const float* bhh  = (const float*)d_in[4];
    const float* Wfc  = (const float*)d_in[5];
    const float* bfc  = (const float*)d_in[6];
    float* out = (float*)d_out;

    char* ws = (char*)d_ws;
    // ws layout (total ~38.3 MB):
    float*          WihT = (float*)ws;                                  // 4 MB
    unsigned short* wfch = (unsigned short*)(ws + 4194304);             // 256 KB
    unsigned short* wfcl = (unsigned short*)(ws + 4194304 + 262144);    // 256 KB
    unsigned short* hsh  = (unsigned short*)(ws + 4718592);             // 16 MB
    unsigned short* hsl  = (unsigned short*)(ws + 4718592 + 16777216);  // 16 MB

    k_transpose<<<256, 256, 0, stream>>>(Wih, WihT);
    k_prep<<<512, 256, 0, stream>>>(Wfc, wfch, wfcl);
    k_rnn<<<64, 256, 0, stream>>>(x, WihT, Whh, bih, bhh, hsh, hsl);
    k_fc<<<1024, 256, 0, stream>>>(hsh, hsl, wfch, wfcl, bfc, out);
}

// Round 2
// 1128.492 us; speedup vs baseline: 1.0913x; 1.0913x over previous
//
#include <hip/hip_runtime.h>

#define V 4096
#define H 256
#define O 512
#define B 64
#define T 512

typedef __attribute__((ext_vector_type(8))) short bf16x8;
typedef __attribute__((ext_vector_type(4))) float f32x4;
typedef __attribute__((ext_vector_type(2))) float f32x2;

__device__ __forceinline__ unsigned short f2bf(float f) {
    unsigned int u = __float_as_uint(f);
    u += 0x7fffu + ((u >> 16) & 1u);   // round-to-nearest-even
    return (unsigned short)(u >> 16);
}
__device__ __forceinline__ float bf2f(unsigned short s) {
    return __uint_as_float(((unsigned int)s) << 16);
}

// ---------------------------------------------------------------------------
// K1a: transpose W_ih [H][V] -> WihT [V][H] so the per-step gather row read
// in k_rnn is coalesced (1 KB contiguous per row).
// ---------------------------------------------------------------------------
__global__ __launch_bounds__(256) void k_transpose(const float* __restrict__ Wih,
                                                   float* __restrict__ WihT) {
    __shared__ float tile[64][65];
    const int bi = blockIdx.x & 3;
    const int bv = blockIdx.x >> 2;
    const int tx = threadIdx.x & 63, ty = threadIdx.x >> 6;
#pragma unroll
    for (int s = 0; s < 16; ++s) {
        int r = ty + 4 * s;
        tile[r][tx] = Wih[(size_t)(bi * 64 + r) * V + bv * 64 + tx];
    }
    __syncthreads();
#pragma unroll
    for (int s = 0; s < 16; ++s) {
        int r = ty + 4 * s;
        WihT[(size_t)(bv * 64 + r) * H + bi * 64 + tx] = tile[tx][r];
    }
}

// ---------------------------------------------------------------------------
// K1b: split W_fc into bf16 hi + bf16 lo for the 3-MFMA FC.
// ---------------------------------------------------------------------------
__global__ __launch_bounds__(256) void k_prep(const float* __restrict__ Wfc,
                                              unsigned short* __restrict__ hi,
                                              unsigned short* __restrict__ lo) {
    int i = blockIdx.x * 256 + threadIdx.x;
    float w = Wfc[i];
    unsigned short h = f2bf(w);
    hi[i] = h;
    lo[i] = f2bf(w - bf2f(h));
}

// ---------------------------------------------------------------------------
// K2: persistent RNN. 64 blocks (one per batch) x 1024 threads (4 waves/SIMD).
// Thread (i = tid>>2, c = tid&3): partial dot of 64 k-terms for output i.
// Quad shuffle-reduce (xor 1,2) -> no reduce barrier; 1 barrier/step.
// Weights: 64 VGPRs/thread (no spill). hs stores delayed 1 step; xp gather
// prefetched 1 step ahead -> HBM latency hidden under the dot.
// ---------------------------------------------------------------------------
__global__ __launch_bounds__(1024, 1) void k_rnn(
    const int* __restrict__ x, const float* __restrict__ WihT,
    const float* __restrict__ Whh, const float* __restrict__ b_ih,
    const float* __restrict__ b_hh,
    unsigned short* __restrict__ hs_hi, unsigned short* __restrict__ hs_lo) {
    __shared__ float hsm[2][H];
    __shared__ int xs[T];
    const int b = blockIdx.x;
    const int tid = threadIdx.x;
    const int i = tid >> 2;   // output index 0..255
    const int c = tid & 3;    // k-chunk 0..3 (64 terms each)

    // W_hh[i][c*64 .. c*64+64) -> 32 x f32x2 = 64 VGPRs
    f32x2 wv[32];
    {
        const f32x2* wr = (const f32x2*)(Whh + (size_t)i * H + c * 64);
#pragma unroll
        for (int j = 0; j < 32; ++j) wv[j] = wr[j];
    }
    if (tid < T) xs[tid] = x[b * T + tid];
    if (tid < H) hsm[0][tid] = 0.0f;
    const float bias = b_ih[i] + b_hh[i];
    __syncthreads();

    unsigned short* ph = hs_hi + (size_t)b * T * H + i;
    unsigned short* pl = hs_lo + (size_t)b * T * H + i;

    float xp_cur = WihT[(size_t)xs[0] * H + i];
    unsigned short hh_prev = 0, hl_prev = 0;

    for (int t = 0; t < T; ++t) {
        // store h_{t-1}: issued here, drains during this step's dot
        if (t > 0) {
            if (c == 1) ph[(size_t)(t - 1) * H] = hh_prev;
            if (c == 2) pl[(size_t)(t - 1) * H] = hl_prev;
        }
        // prefetch next step's gather (consumed next iteration)
        int tn = (t + 1 < T) ? t + 1 : t;
        float xp_next = WihT[(size_t)xs[tn] * H + i];

        const f32x4* hv = (const f32x4*)hsm[t & 1] + c * 16;
        f32x2 a0 = {0.f, 0.f}, a1 = {0.f, 0.f}, a2 = {0.f, 0.f}, a3 = {0.f, 0.f};
#pragma unroll
        for (int j = 0; j < 16; ++j) {
            f32x4 h4 = hv[j];                     // 4 distinct 16B/wave: ~free
            f32x2 ha = {h4[0], h4[1]}, hb = {h4[2], h4[3]};
            if (j & 1) { a2 += ha * wv[2 * j]; a3 += hb * wv[2 * j + 1]; }
            else       { a0 += ha * wv[2 * j]; a1 += hb * wv[2 * j + 1]; }
        }
        f32x2 as = (a0 + a1) + (a2 + a3);
        float sum = as[0] + as[1];
        sum += __shfl_xor(sum, 1);                // quad reduce: c-partials
        sum += __shfl_xor(sum, 2);

        float pre = sum + xp_cur + bias;
        float e = __expf(2.0f * pre);             // tanh = 1 - 2/(e^{2x}+1)
        float hval = 1.0f - 2.0f * __builtin_amdgcn_rcpf(e + 1.0f);

        if (c == 0) hsm[(t + 1) & 1][i] = hval;   // write other buffer
        hh_prev = f2bf(hval);
        hl_prev = f2bf(hval - bf2f(hh_prev));
        xp_cur = xp_next;
        __syncthreads();                          // single barrier per step
    }
    // final step's store
    if (c == 1) ph[(size_t)(T - 1) * H] = hh_prev;
    if (c == 2) pl[(size_t)(T - 1) * H] = hl_prev;
}

// ---------------------------------------------------------------------------
// K3: FC GEMM [32768,256] x [256,512] via 3-split bf16 MFMA.
// 128x128 tile, BK=64, 4 waves (2x2, 64x64 each), XOR-swizzled LDS.
// ---------------------------------------------------------------------------
__global__ __launch_bounds__(256, 2) void k_fc(
    const unsigned short* __restrict__ hs_hi, const unsigned short* __restrict__ hs_lo,
    const unsigned short* __restrict__ wfc_hi, const unsigned short* __restrict__ wfc_lo,
    const float* __restrict__ b_fc, float* __restrict__ out) {
    __shared__ short sAh[128 * 64], sAl[128 * 64], sBh[128 * 64], sBl[128 * 64];
    const int tid = threadIdx.x;
    const int bm = blockIdx.x >> 2, bn = blockIdx.x & 3;
    const int m0 = bm * 128, n0 = bn * 128;
    const int w = tid >> 6, lane = tid & 63;
    const int wm = w >> 1, wn = w & 1;
    const int l16 = lane & 15, g = lane >> 4;

    f32x4 acc[4][4];
#pragma unroll
    for (int a = 0; a < 4; ++a)
#pragma unroll
        for (int cc = 0; cc < 4; ++cc)
#pragma unroll
            for (int q = 0; q < 4; ++q) acc[a][cc][q] = 0.0f;

    for (int kt = 0; kt < 4; ++kt) {
        const int k0 = kt * 64;
#pragma unroll
        for (int s = 0; s < 4; ++s) {
            int cidx = tid + 256 * s;
            int r = cidx >> 3, slot = cidx & 7;
            int dst = r * 64 + ((slot ^ (r & 7)) << 3);
            size_t ga = (size_t)(m0 + r) * 256 + k0 + slot * 8;
            *(bf16x8*)&sAh[dst] = *(const bf16x8*)&hs_hi[ga];
            *(bf16x8*)&sAl[dst] = *(const bf16x8*)&hs_lo[ga];
            size_t gb = (size_t)(n0 + r) * 256 + k0 + slot * 8;
            *(bf16x8*)&sBh[dst] = *(const bf16x8*)&wfc_hi[gb];
            *(bf16x8*)&sBl[dst] = *(const bf16x8*)&wfc_lo[gb];
        }
        __syncthreads();
#pragma unroll
        for (int kc = 0; kc < 2; ++kc) {
            bf16x8 ah[4], al[4], bh[4], bl[4];
            const int slot = kc * 4 + g;
#pragma unroll
            for (int mi = 0; mi < 4; ++mi) {
                int r = wm * 64 + mi * 16 + l16;
                int off = r * 64 + ((slot ^ (r & 7)) << 3);
                ah[mi] = *(const bf16x8*)&sAh[off];
                al[mi] = *(const bf16x8*)&sAl[off];
            }
#pragma unroll
            for (int ni = 0; ni < 4; ++ni) {
                int r = wn * 64 + ni * 16 + l16;
                int off = r * 64 + ((slot ^ (r & 7)) << 3);
                bh[ni] = *(const bf16x8*)&sBh[off];
                bl[ni] = *(const bf16x8*)&sBl[off];
            }
#pragma unroll
            for (int mi = 0; mi < 4; ++mi)
#pragma unroll
                for (int ni = 0; ni < 4; ++ni) {
                    acc[mi][ni] = __builtin_amdgcn_mfma_f32_16x16x32_bf16(
                        ah[mi], bh[ni], acc[mi][ni], 0, 0, 0);
                    acc[mi][ni] = __builtin_amdgcn_mfma_f32_16x16x32_bf16(
                        ah[mi], bl[ni], acc[mi][ni], 0, 0, 0);
                    acc[mi][ni] = __builtin_amdgcn_mfma_f32_16x16x32_bf16(
                        al[mi], bh[ni], acc[mi][ni], 0, 0, 0);
                }
        }
        __syncthreads();
    }
#pragma unroll
    for (int ni = 0; ni < 4; ++ni) {
        int n = n0 + wn * 64 + ni * 16 + l16;
        float bfc = b_fc[n];
#pragma unroll
        for (int mi = 0; mi < 4; ++mi) {
#pragma unroll
            for (int q = 0; q < 4; ++q) {
                int m = m0 + wm * 64 + mi * 16 + g * 4 + q;
                out[(size_t)m * O + n] = acc[mi][ni][q] + bfc;
            }
        }
    }
}

extern "C" void kernel_launch(void* const* d_in, const int* in_sizes, int n_in,
                              void* d_out, int out_size, void* d_ws, size_t ws_size,
                              hipStream_t stream) {
    (void)in_sizes; (void)n_in; (void)out_size; (void)ws_size;
    const int*   x    = (const int*)d_in[0];
    const float* Wih  = (const float*)d_in[1];
    const float* Whh  = (const float*)d_in[2];
    const float* bih  = (const float*)d_in[3];
    const float* bhh  = (const float*)d_in[4];
    const float* Wfc  = (const float*)d_in[5];
    const float* bfc  = (const float*)d_in[6];
    float* out = (float*)d_out;

    char* ws = (char*)d_ws;
    float*          WihT = (float*)ws;                                  // 4 MB
    unsigned short* wfch = (unsigned short*)(ws + 4194304);             // 256 KB
    unsigned short* wfcl = (unsigned short*)(ws + 4194304 + 262144);    // 256 KB
    unsigned short* hsh  = (unsigned short*)(ws + 4718592);             // 16 MB
    unsigned short* hsl  = (unsigned short*)(ws + 4718592 + 16777216);  // 16 MB

    k_transpose<<<256, 256, 0, stream>>>(Wih, WihT);
    k_prep<<<512, 256, 0, stream>>>(Wfc, wfch, wfcl);
    k_rnn<<<64, 1024, 0, stream>>>(x, WihT, Whh, bih, bhh, hsh, hsl);
    k_fc<<<1024, 256, 0, stream>>>(hsh, hsl, wfch, wfcl, bfc, out);
}

// Round 3
// 395.395 us; speedup vs baseline: 3.1146x; 2.8541x over previous
//
#include <hip/hip_runtime.h>

#define V 4096
#define H 256
#define O 512
#define B 64
#define T 512

typedef __attribute__((ext_vector_type(8))) short bf16x8;
typedef __attribute__((ext_vector_type(4))) float f32x4;
typedef __attribute__((ext_vector_type(2))) float f32x2;

__device__ __forceinline__ unsigned short f2bf(float f) {
    unsigned int u = __float_as_uint(f);
    u += 0x7fffu + ((u >> 16) & 1u);   // round-to-nearest-even
    return (unsigned short)(u >> 16);
}
__device__ __forceinline__ float bf2f(unsigned short s) {
    return __uint_as_float(((unsigned int)s) << 16);
}

// ---------------------------------------------------------------------------
// K1a: transpose W_ih [H][V] -> WihT [V][H] so the per-step gather row read
// in k_rnn is coalesced.
// ---------------------------------------------------------------------------
__global__ __launch_bounds__(256) void k_transpose(const float* __restrict__ Wih,
                                                   float* __restrict__ WihT) {
    __shared__ float tile[64][65];
    const int bi = blockIdx.x & 3;
    const int bv = blockIdx.x >> 2;
    const int tx = threadIdx.x & 63, ty = threadIdx.x >> 6;
#pragma unroll
    for (int s = 0; s < 16; ++s) {
        int r = ty + 4 * s;
        tile[r][tx] = Wih[(size_t)(bi * 64 + r) * V + bv * 64 + tx];
    }
    __syncthreads();
#pragma unroll
    for (int s = 0; s < 16; ++s) {
        int r = ty + 4 * s;
        WihT[(size_t)(bv * 64 + r) * H + bi * 64 + tx] = tile[tx][r];
    }
}

// ---------------------------------------------------------------------------
// K1b: split W_fc into bf16 hi + bf16 lo for the 3-MFMA FC.
// ---------------------------------------------------------------------------
__global__ __launch_bounds__(256) void k_prep(const float* __restrict__ Wfc,
                                              unsigned short* __restrict__ hi,
                                              unsigned short* __restrict__ lo) {
    int i = blockIdx.x * 256 + threadIdx.x;
    float w = Wfc[i];
    unsigned short h = f2bf(w);
    hi[i] = h;
    lo[i] = f2bf(w - bf2f(h));
}

// ---------------------------------------------------------------------------
// K2: persistent RNN. 64 blocks (one per batch) x 512 threads (2 waves/SIMD).
// Thread (i = tid>>2, c = tid&3): rows {2i, 2i+1}, k-quarter c (64 terms).
// Weights: 64 x f32x2 = 128 VGPRs, pinned with asm keep-alives (defeats
// rematerialization that caused VGPR_Count=48 + per-step reloads in R2).
// h in LDS with chunk stride 68 floats (4-float pad): the 4 c-groups read
// 4 disjoint bank quads -> zero conflicts (was 1e8 conflict cycles).
// Quad shuffle-reduce; xp gather prefetched 1 step; hs stores delayed 1 step.
// ---------------------------------------------------------------------------
#define CH 68   // padded chunk stride in floats (64 data + 4 pad)

__global__ __launch_bounds__(512, 2) void k_rnn(
    const int* __restrict__ x, const float* __restrict__ WihT,
    const float* __restrict__ Whh, const float* __restrict__ b_ih,
    const float* __restrict__ b_hh,
    unsigned short* __restrict__ hs_hi, unsigned short* __restrict__ hs_lo) {
    __shared__ float hsm[2][4 * CH];
    __shared__ int xs[T];
    const int b = blockIdx.x;
    const int tid = threadIdx.x;
    const int i = tid >> 2;     // row-pair index 0..127
    const int c = tid & 3;      // k-quarter 0..3
    const int r0 = 2 * i;

    // W_hh rows r0, r0+1, k-range [c*64, c*64+64): 64 f32x2 = 128 VGPRs
    f32x2 w0[32], w1[32];
    {
        const f32x2* wr0 = (const f32x2*)(Whh + (size_t)r0 * H + c * 64);
        const f32x2* wr1 = (const f32x2*)(Whh + (size_t)(r0 + 1) * H + c * 64);
#pragma unroll
        for (int j = 0; j < 32; ++j) { w0[j] = wr0[j]; w1[j] = wr1[j]; }
    }
#pragma unroll
    for (int j = 0; j < 32; ++j) {
        asm volatile("" : "+v"(w0[j]));   // opaque: cannot be rematerialized
        asm volatile("" : "+v"(w1[j]));
    }

    xs[tid] = x[b * T + tid];
    if (tid < 4 * CH) hsm[0][tid] = 0.0f;
    f32x2 bias;
    bias[0] = b_ih[r0] + b_hh[r0];
    bias[1] = b_ih[r0 + 1] + b_hh[r0 + 1];
    __syncthreads();

    unsigned int* ph = (unsigned int*)(hs_hi + (size_t)b * T * H) + i;  // packed row-pairs
    unsigned int* pl = (unsigned int*)(hs_lo + (size_t)b * T * H) + i;

    f32x2 xp_cur = *(const f32x2*)(WihT + (size_t)xs[0] * H + r0);
    unsigned int hh_prev = 0, hl_prev = 0;

    for (int t = 0; t < T; ++t) {
        // store h_{t-1} (issued here, drains under this step's dot)
        if (t > 0) {
            if (c == 1) ph[(size_t)(t - 1) * 128] = hh_prev;
            if (c == 2) pl[(size_t)(t - 1) * 128] = hl_prev;
        }
        // prefetch next step's gather row (consumed next iteration)
        int tn = (t + 1 < T) ? t + 1 : t;
        f32x2 xp_next = *(const f32x2*)(WihT + (size_t)xs[tn] * H + r0);

        const f32x4* hv = (const f32x4*)(hsm[t & 1] + c * CH);
        f32x2 a0 = {0.f, 0.f}, a1 = {0.f, 0.f}, a2 = {0.f, 0.f}, a3 = {0.f, 0.f};
#pragma unroll
        for (int j = 0; j < 16; ++j) {
            f32x4 h4 = hv[j];                 // broadcast within c-group; quads disjoint
            f32x2 hA = {h4[0], h4[1]}, hB = {h4[2], h4[3]};
            a0 += hA * w0[2 * j]; a1 += hB * w0[2 * j + 1];   // row r0, pk over k
            a2 += hA * w1[2 * j]; a3 += hB * w1[2 * j + 1];   // row r0+1
        }
        f32x2 s01 = a0 + a1, s23 = a2 + a3;
        float s0 = s01[0] + s01[1];           // row r0 partial (this c)
        float s1 = s23[0] + s23[1];           // row r0+1 partial
        s0 += __shfl_xor(s0, 1); s1 += __shfl_xor(s1, 1);
        s0 += __shfl_xor(s0, 2); s1 += __shfl_xor(s1, 2);

        float p0 = s0 + xp_cur[0] + bias[0];
        float p1 = s1 + xp_cur[1] + bias[1];
        float e0 = __expf(2.0f * p0), e1 = __expf(2.0f * p1);
        float h0 = 1.0f - 2.0f * __builtin_amdgcn_rcpf(e0 + 1.0f);
        float h1 = 1.0f - 2.0f * __builtin_amdgcn_rcpf(e1 + 1.0f);

        if (c == 0) {   // write next h (padded layout), f32x2: 8B aligned
            f32x2 hw = {h0, h1};
            *(f32x2*)&hsm[(t + 1) & 1][(r0 >> 6) * CH + (r0 & 63)] = hw;
        }
        unsigned short hh0 = f2bf(h0), hh1 = f2bf(h1);
        hh_prev = (unsigned int)hh0 | ((unsigned int)hh1 << 16);
        unsigned short hl0 = f2bf(h0 - bf2f(hh0)), hl1 = f2bf(h1 - bf2f(hh1));
        hl_prev = (unsigned int)hl0 | ((unsigned int)hl1 << 16);
        xp_cur = xp_next;
        __syncthreads();                      // single barrier per step
    }
    if (c == 1) ph[(size_t)(T - 1) * 128] = hh_prev;
    if (c == 2) pl[(size_t)(T - 1) * 128] = hl_prev;
}

// ---------------------------------------------------------------------------
// K3: FC GEMM [32768,256] x [256,512] via 3-split bf16 MFMA.
// 128x128 tile, BK=64, 4 waves (2x2, 64x64 each), XOR-swizzled LDS.
// ---------------------------------------------------------------------------
__global__ __launch_bounds__(256, 2) void k_fc(
    const unsigned short* __restrict__ hs_hi, const unsigned short* __restrict__ hs_lo,
    const unsigned short* __restrict__ wfc_hi, const unsigned short* __restrict__ wfc_lo,
    const float* __restrict__ b_fc, float* __restrict__ out) {
    __shared__ short sAh[128 * 64], sAl[128 * 64], sBh[128 * 64], sBl[128 * 64];
    const int tid = threadIdx.x;
    const int bm = blockIdx.x >> 2, bn = blockIdx.x & 3;
    const int m0 = bm * 128, n0 = bn * 128;
    const int w = tid >> 6, lane = tid & 63;
    const int wm = w >> 1, wn = w & 1;
    const int l16 = lane & 15, g = lane >> 4;

    f32x4 acc[4][4];
#pragma unroll
    for (int a = 0; a < 4; ++a)
#pragma unroll
        for (int cc = 0; cc < 4; ++cc)
#pragma unroll
            for (int q = 0; q < 4; ++q) acc[a][cc][q] = 0.0f;

    for (int kt = 0; kt < 4; ++kt) {
        const int k0 = kt * 64;
#pragma unroll
        for (int s = 0; s < 4; ++s) {
            int cidx = tid + 256 * s;
            int r = cidx >> 3, slot = cidx & 7;
            int dst = r * 64 + ((slot ^ (r & 7)) << 3);
            size_t ga = (size_t)(m0 + r) * 256 + k0 + slot * 8;
            *(bf16x8*)&sAh[dst] = *(const bf16x8*)&hs_hi[ga];
            *(bf16x8*)&sAl[dst] = *(const bf16x8*)&hs_lo[ga];
            size_t gb = (size_t)(n0 + r) * 256 + k0 + slot * 8;
            *(bf16x8*)&sBh[dst] = *(const bf16x8*)&wfc_hi[gb];
            *(bf16x8*)&sBl[dst] = *(const bf16x8*)&wfc_lo[gb];
        }
        __syncthreads();
#pragma unroll
        for (int kc = 0; kc < 2; ++kc) {
            bf16x8 ah[4], al[4], bh[4], bl[4];
            const int slot = kc * 4 + g;
#pragma unroll
            for (int mi = 0; mi < 4; ++mi) {
                int r = wm * 64 + mi * 16 + l16;
                int off = r * 64 + ((slot ^ (r & 7)) << 3);
                ah[mi] = *(const bf16x8*)&sAh[off];
                al[mi] = *(const bf16x8*)&sAl[off];
            }
#pragma unroll
            for (int ni = 0; ni < 4; ++ni) {
                int r = wn * 64 + ni * 16 + l16;
                int off = r * 64 + ((slot ^ (r & 7)) << 3);
                bh[ni] = *(const bf16x8*)&sBh[off];
                bl[ni] = *(const bf16x8*)&sBl[off];
            }
#pragma unroll
            for (int mi = 0; mi < 4; ++mi)
#pragma unroll
                for (int ni = 0; ni < 4; ++ni) {
                    acc[mi][ni] = __builtin_amdgcn_mfma_f32_16x16x32_bf16(
                        ah[mi], bh[ni], acc[mi][ni], 0, 0, 0);
                    acc[mi][ni] = __builtin_amdgcn_mfma_f32_16x16x32_bf16(
                        ah[mi], bl[ni], acc[mi][ni], 0, 0, 0);
                    acc[mi][ni] = __builtin_amdgcn_mfma_f32_16x16x32_bf16(
                        al[mi], bh[ni], acc[mi][ni], 0, 0, 0);
                }
        }
        __syncthreads();
    }
#pragma unroll
    for (int ni = 0; ni < 4; ++ni) {
        int n = n0 + wn * 64 + ni * 16 + l16;
        float bfc = b_fc[n];
#pragma unroll
        for (int mi = 0; mi < 4; ++mi) {
#pragma unroll
            for (int q = 0; q < 4; ++q) {
                int m = m0 + wm * 64 + mi * 16 + g * 4 + q;
                out[(size_t)m * O + n] = acc[mi][ni][q] + bfc;
            }
        }
    }
}

extern "C" void kernel_launch(void* const* d_in, const int* in_sizes, int n_in,
                              void* d_out, int out_size, void* d_ws, size_t ws_size,
                              hipStream_t stream) {
    (void)in_sizes; (void)n_in; (void)out_size; (void)ws_size;
    const int*   x    = (const int*)d_in[0];
    const float* Wih  = (const float*)d_in[1];
    const float* Whh  = (const float*)d_in[2];
    const float* bih  = (const float*)d_in[3];
    const float* bhh  = (const float*)d_in[4];
    const float* Wfc  = (const float*)d_in[5];
    const float* bfc  = (const float*)d_in[6];
    float* out = (float*)d_out;

    char* ws = (char*)d_ws;
    float*          WihT = (float*)ws;                                  // 4 MB
    unsigned short* wfch = (unsigned short*)(ws + 4194304);             // 256 KB
    unsigned short* wfcl = (unsigned short*)(ws + 4194304 + 262144);    // 256 KB
    unsigned short* hsh  = (unsigned short*)(ws + 4718592);             // 16 MB
    unsigned short* hsl  = (unsigned short*)(ws + 4718592 + 16777216);  // 16 MB

    k_transpose<<<256, 256, 0, stream>>>(Wih, WihT);
    k_prep<<<512, 256, 0, stream>>>(Wfc, wfch, wfcl);
    k_rnn<<<64, 512, 0, stream>>>(x, WihT, Whh, bih, bhh, hsh, hsl);
    k_fc<<<1024, 256, 0, stream>>>(hsh, hsl, wfch, wfcl, bfc, out);
}